// Round 5
// baseline (497.845 us; speedup 1.0000x reference)
//
#include <hip/hip_runtime.h>
#include <hip/hip_bf16.h>
#include <math.h>

#define BB 2
#define SS 2048
#define DD 2048
#define HH 16
#define DHH 128
#define MM (BB*SS)   // 4096

typedef __attribute__((ext_vector_type(8))) short bf16x8;
typedef __attribute__((ext_vector_type(4))) float f32x4;

#define AS1 __attribute__((address_space(1)))
#define AS3 __attribute__((address_space(3)))
#define GLOAD_LDS16(g, l) __builtin_amdgcn_global_load_lds((const AS1 void*)(g), (AS3 void*)(l), 16, 0, 0)

__device__ __forceinline__ float b2f(short s) {
  union { unsigned int u; float f; } v;
  v.u = ((unsigned int)(unsigned short)s) << 16;
  return v.f;
}
__device__ __forceinline__ short f2b(float f) {
  union { float f; unsigned int u; } v; v.f = f;
  unsigned int u = v.u;
  u += 0x7fffu + ((u >> 16) & 1u);   // round-to-nearest-even
  return (short)(u >> 16);
}
// fast round-half-up; valid for non-negative finite values (P in [0,1])
__device__ __forceinline__ short f2b_fast(float f) {
  union { float f; unsigned int u; } v; v.f = f;
  return (short)((v.u + 0x8000u) >> 16);
}

// ---- DPP 16-lane reductions (VALU pipe, no LDS ops) ----
template<int CTRL>
__device__ __forceinline__ float dppf(float x) {
  int xi = __builtin_bit_cast(int, x);
  int r = __builtin_amdgcn_update_dpp(0, xi, CTRL, 0xf, 0xf, true);
  return __builtin_bit_cast(float, r);
}
__device__ __forceinline__ float rmax16(float x) {
  x = fmaxf(x, dppf<0xB1>(x));   // quad_perm xor1
  x = fmaxf(x, dppf<0x4E>(x));   // quad_perm xor2
  x = fmaxf(x, dppf<0x141>(x));  // row_half_mirror
  x = fmaxf(x, dppf<0x140>(x));  // row_mirror
  return x;
}
__device__ __forceinline__ float rsum16(float x) {
  x += dppf<0xB1>(x);
  x += dppf<0x4E>(x);
  x += dppf<0x141>(x);
  x += dppf<0x140>(x);
  return x;
}

// ---------------- fp32 -> bf16 convert, all 5 tensors in one launch ----------------
__global__ void cvt_all(const float* __restrict__ x,  const float* __restrict__ wq,
                        const float* __restrict__ wk, const float* __restrict__ wv,
                        const float* __restrict__ wo,
                        short* __restrict__ xb,  short* __restrict__ wqb,
                        short* __restrict__ wkb, short* __restrict__ wvb,
                        short* __restrict__ wob) {
  int i = blockIdx.x * blockDim.x + threadIdx.x;   // float4 index
  const float* src; short* dst; int off;
  if (i < 2097152) { src = x; dst = xb; off = i; }
  else {
    int j = i - 2097152;
    int w = j >> 20; off = j & 1048575;
    src = (w == 0) ? wq : (w == 1) ? wk : (w == 2) ? wv : wo;
    dst = (w == 0) ? wqb : (w == 1) ? wkb : (w == 2) ? wvb : wob;
  }
  float4 v = ((const float4*)src)[off];
  short4 o;
  o.x = f2b(v.x); o.y = f2b(v.y); o.z = f2b(v.z); o.w = f2b(v.w);
  ((short4*)dst)[off] = o;
}

// ---------------- Fused QKV GEMM: N = 6144 over three weight mats ----------------
__global__ __launch_bounds__(256)
void gemm_qkv(const short* __restrict__ A,
              const short* __restrict__ Wq, const short* __restrict__ Wk,
              const short* __restrict__ Wv,
              short* __restrict__ Qo, short* __restrict__ Ko, short* __restrict__ Vo) {
  __shared__ __align__(16) short As[128*64];
  __shared__ __align__(16) short Bs[128*64];
  const int tid = threadIdx.x;
  const int lane = tid & 63;
  const int wave = tid >> 6;
  const int wm = wave >> 1, wn = wave & 1;
  const int quad = lane >> 4, l16 = lane & 15;
  const int wsel = blockIdx.x >> 4;           // 0=Q 1=K 2=V
  const short* Bw = Wq; short* Cout = Qo;
  if (wsel == 1) { Bw = Wk; Cout = Ko; }
  else if (wsel == 2) { Bw = Wv; Cout = Vo; }
  const int bn = (blockIdx.x & 15) * 128;
  const int bm = blockIdx.y * 128;
  const int K = DD;

  const int srow = tid >> 3;
  const int scol = (tid & 7) * 8;
  const short* aBase = A + (size_t)(bm + srow) * K + scol;
  const short* bBase = Bw + (size_t)(bn + srow) * K + scol;
  f32x4 acc[4][4] = {};

  for (int k0 = 0; k0 < K; k0 += 64) {
    #pragma unroll
    for (int j = 0; j < 4; ++j) {
      GLOAD_LDS16(aBase + (size_t)j * 32 * K + k0, As + j * 2048 + wave * 512);
      GLOAD_LDS16(bBase + (size_t)j * 32 * K + k0, Bs + j * 2048 + wave * 512);
    }
    __syncthreads();
    #pragma unroll
    for (int kk = 0; kk < 64; kk += 32) {
      bf16x8 af[4], bf[4];
      #pragma unroll
      for (int t = 0; t < 4; ++t)
        af[t] = *(const bf16x8*)&As[(wm*64 + t*16 + l16) * 64 + kk + quad*8];
      #pragma unroll
      for (int t = 0; t < 4; ++t)
        bf[t] = *(const bf16x8*)&Bs[(wn*64 + t*16 + l16) * 64 + kk + quad*8];
      #pragma unroll
      for (int mt = 0; mt < 4; ++mt)
        #pragma unroll
        for (int nt = 0; nt < 4; ++nt)
          acc[mt][nt] = __builtin_amdgcn_mfma_f32_16x16x32_bf16(af[mt], bf[nt], acc[mt][nt], 0, 0, 0);
    }
    __syncthreads();
  }

  #pragma unroll
  for (int mt = 0; mt < 4; ++mt)
    #pragma unroll
    for (int nt = 0; nt < 4; ++nt)
      #pragma unroll
      for (int r = 0; r < 4; ++r) {
        int m = bm + wm*64 + mt*16 + quad*4 + r;
        int n = bn + wn*64 + nt*16 + l16;
        int b = m >> 11, s = m & 2047;
        int h = n >> 7,  d = n & 127;
        Cout[(((size_t)(b*HH + h)*SS + s)*DHH) + d] = f2b(acc[mt][nt][r]);
      }
}

// ---------------- O-projection GEMM, split-K=2, bf16 partials ----------------
// A: bf16 [M,2048]; W: bf16 [2048,2048]; Pout: bf16 partials, 2 x [M,2048]
__global__ __launch_bounds__(256)
void gemm_o_sk(const short* __restrict__ A, const short* __restrict__ Bw,
               short* __restrict__ Pout) {
  __shared__ __align__(16) short As[128*64];
  __shared__ __align__(16) short Bs[128*64];
  const int tid = threadIdx.x;
  const int lane = tid & 63;
  const int wave = tid >> 6;
  const int wm = wave >> 1, wn = wave & 1;
  const int quad = lane >> 4, l16 = lane & 15;
  const int bm = blockIdx.y * 128, bn = blockIdx.x * 128;
  const int ks = blockIdx.z;                 // 0 or 1
  const int kbeg = ks * 1024, kend = kbeg + 1024;
  const int K = DD;                          // row stride

  const int srow = tid >> 3;
  const int scol = (tid & 7) * 8;
  const short* aBase = A + (size_t)(bm + srow) * K + scol;
  const short* bBase = Bw + (size_t)(bn + srow) * K + scol;
  short* Pp = Pout + (size_t)ks * MM * DD;
  f32x4 acc[4][4] = {};

  for (int k0 = kbeg; k0 < kend; k0 += 64) {
    #pragma unroll
    for (int j = 0; j < 4; ++j) {
      GLOAD_LDS16(aBase + (size_t)j * 32 * K + k0, As + j * 2048 + wave * 512);
      GLOAD_LDS16(bBase + (size_t)j * 32 * K + k0, Bs + j * 2048 + wave * 512);
    }
    __syncthreads();
    #pragma unroll
    for (int kk = 0; kk < 64; kk += 32) {
      bf16x8 af[4], bf[4];
      #pragma unroll
      for (int t = 0; t < 4; ++t)
        af[t] = *(const bf16x8*)&As[(wm*64 + t*16 + l16) * 64 + kk + quad*8];
      #pragma unroll
      for (int t = 0; t < 4; ++t)
        bf[t] = *(const bf16x8*)&Bs[(wn*64 + t*16 + l16) * 64 + kk + quad*8];
      #pragma unroll
      for (int mt = 0; mt < 4; ++mt)
        #pragma unroll
        for (int nt = 0; nt < 4; ++nt)
          acc[mt][nt] = __builtin_amdgcn_mfma_f32_16x16x32_bf16(af[mt], bf[nt], acc[mt][nt], 0, 0, 0);
    }
    __syncthreads();
  }

  #pragma unroll
  for (int mt = 0; mt < 4; ++mt)
    #pragma unroll
    for (int nt = 0; nt < 4; ++nt)
      #pragma unroll
      for (int r = 0; r < 4; ++r) {
        int m = bm + wm*64 + mt*16 + quad*4 + r;
        int n = bn + wn*64 + nt*16 + l16;
        Pp[(size_t)m * DD + n] = f2b(acc[mt][nt][r]);
      }
}

// ---------------- sum two bf16 partials -> fp32 out ----------------
__global__ void add_out(const short* __restrict__ P, float* __restrict__ out, int n4) {
  int i = blockIdx.x * blockDim.x + threadIdx.x;
  if (i >= n4) return;
  short4 a = ((const short4*)P)[i];
  short4 b = ((const short4*)(P + (size_t)MM * DD))[i];
  float4 o;
  o.x = b2f(a.x) + b2f(b.x);
  o.y = b2f(a.y) + b2f(b.y);
  o.z = b2f(a.z) + b2f(b.z);
  o.w = b2f(a.w) + b2f(b.w);
  ((float4*)out)[i] = o;
}

// ---------------- RoPE (interleaved), Q and K in one launch ----------------
// blockIdx.y == 0 -> Q (also folds in 1/sqrt(DH)); == 1 -> K
__global__ void rope2(short* __restrict__ Qt, short* __restrict__ Kt,
                      const int* __restrict__ pos) {
  int idx = blockIdx.x * blockDim.x + threadIdx.x;
  short* T = (blockIdx.y == 0) ? Qt : Kt;
  const float post = (blockIdx.y == 0) ? 0.08838834764831845f : 1.0f;
  int g = idx & 15;
  int rowid = idx >> 4;
  int s = rowid & (SS - 1);
  short* p = T + (size_t)rowid * DHH + g * 8;
  float fp = (float)pos[s];
  int4 raw = *(int4*)p;
  short* e = (short*)&raw;
  #pragma unroll
  for (int j = 0; j < 4; ++j) {
    int pi = g * 4 + j;
    float fr = expf(-0.14391156831f * (float)pi);  // theta^(-pi/64)
    float ang = fp * fr;
    float sn, cs;
    sincosf(ang, &sn, &cs);
    float xe = b2f(e[2*j]), xo = b2f(e[2*j+1]);
    float oe = (xe * cs - xo * sn) * post;
    float oo = (xe * sn + xo * cs) * post;
    e[2*j]   = f2b(oe);
    e[2*j+1] = f2b(oo);
  }
  *(int4*)p = raw;
}

// ---------------- Flash attention (causal), paired 64-row Q tiles ----------------
// Q pre-scaled by 1/sqrt(DH). Block p handles Q tiles qa=p, qb=31-p (33 computes each).
__global__ __launch_bounds__(256, 2)
void attn(const short* __restrict__ Q, const short* __restrict__ K,
          const short* __restrict__ V, short* __restrict__ O) {
  __shared__ __align__(16) short Ks[64*136];    // [key][dim], stride 136
  __shared__ __align__(16) short Vt[128*72];    // [dim][key], stride 72
  __shared__ __align__(16) short Pb[4*32*72];   // per-wave P
  const int tid = threadIdx.x;
  const int lane = tid & 63, wave = tid >> 6;
  const int quad = lane >> 4, l16 = lane & 15;
  const int p = blockIdx.x;            // 0..15
  const int qa = p, qb = 31 - p;
  const int bh = blockIdx.y;
  const int b = bh >> 4, h = bh & 15;
  const short* Kg = K + (size_t)bh * SS * DHH;
  const short* Vg = V + (size_t)bh * SS * DHH;

  bf16x8 aq[2][4];
  #pragma unroll
  for (int t = 0; t < 2; ++t) {
    int qrb = (t ? qb : qa) * 64;
    const short* qp = Q + ((size_t)bh * SS + qrb + wave*16 + l16) * DHH + quad*8;
    #pragma unroll
    for (int ks = 0; ks < 4; ++ks) aq[t][ks] = *(const bf16x8*)(qp + ks*32);
  }

  f32x4 o[2][8] = {};
  float mrow[2][4], lrow[2][4];
  #pragma unroll
  for (int t = 0; t < 2; ++t)
    #pragma unroll
    for (int r = 0; r < 4; ++r) { mrow[t][r] = -1e30f; lrow[t][r] = 0.f; }

  const int krow = tid >> 2;
  const int kseg = (tid & 3) * 32;
  const int vkp  = (tid & 31) * 2;
  const int vds  = (tid >> 5) * 16;

  const int nkt = qb + 1;
  int4 kreg[4], vreg[4];
  {
    const short* kp = Kg + (size_t)krow * DHH + kseg;
    #pragma unroll
    for (int j = 0; j < 4; ++j) kreg[j] = *(const int4*)(kp + j*8);
    const short* vp = Vg + (size_t)vkp * DHH + vds;
    vreg[0] = *(const int4*)(vp);
    vreg[1] = *(const int4*)(vp + 8);
    vreg[2] = *(const int4*)(vp + DHH);
    vreg[3] = *(const int4*)(vp + DHH + 8);
  }

  for (int kt = 0; kt < nkt; ++kt) {
    #pragma unroll
    for (int j = 0; j < 4; ++j)
      *(int4*)&Ks[krow*136 + kseg + j*8] = kreg[j];
    {
      const short* s0 = (const short*)&vreg[0];
      const short* s1 = (const short*)&vreg[2];
      #pragma unroll
      for (int e = 0; e < 16; ++e) {
        int val = (int)(unsigned short)s0[e] | ((int)(unsigned short)s1[e] << 16);
        *(int*)&Vt[(vds + e)*72 + vkp] = val;
      }
    }
    __syncthreads();

    if (kt + 1 < nkt) {
      const short* kp = Kg + (size_t)((kt+1)*64 + krow) * DHH + kseg;
      #pragma unroll
      for (int j = 0; j < 4; ++j) kreg[j] = *(const int4*)(kp + j*8);
      const short* vp = Vg + (size_t)((kt+1)*64 + vkp) * DHH + vds;
      vreg[0] = *(const int4*)(vp);
      vreg[1] = *(const int4*)(vp + 8);
      vreg[2] = *(const int4*)(vp + DHH);
      vreg[3] = *(const int4*)(vp + DHH + 8);
    }

    const bool actA = (kt <= qa);

    float sv[2][4][4];
    #pragma unroll
    for (int nt = 0; nt < 4; ++nt) {
      f32x4 a1 = {0.f,0.f,0.f,0.f}, a0 = {0.f,0.f,0.f,0.f};
      #pragma unroll
      for (int ks = 0; ks < 4; ++ks) {
        bf16x8 bk = *(const bf16x8*)&Ks[(nt*16 + l16)*136 + ks*32 + quad*8];
        a1 = __builtin_amdgcn_mfma_f32_16x16x32_bf16(aq[1][ks], bk, a1, 0, 0, 0);
        if (actA) a0 = __builtin_amdgcn_mfma_f32_16x16x32_bf16(aq[0][ks], bk, a0, 0, 0, 0);
      }
      #pragma unroll
      for (int r = 0; r < 4; ++r) {
        sv[1][nt][r] = a1[r];
        sv[0][nt][r] = a0[r];
      }
    }
    #pragma unroll
    for (int t = 0; t < 2; ++t) {
      int tq = t ? qb : qa;
      if (kt == tq) {
        #pragma unroll
        for (int nt = 0; nt < 4; ++nt)
          #pragma unroll
          for (int r = 0; r < 4; ++r)
            if (nt*16 + l16 > wave*16 + quad*4 + r) sv[t][nt][r] = -1e30f;
      }
    }

    #pragma unroll
    for (int t = 0; t < 2; ++t) {
      if (t == 0 && !actA) continue;
      #pragma unroll
      for (int r = 0; r < 4; ++r) {
        float mx = fmaxf(fmaxf(sv[t][0][r], sv[t][1][r]), fmaxf(sv[t][2][r], sv[t][3][r]));
        mx = rmax16(mx);
        float mnew = fmaxf(mrow[t][r], mx);
        float alpha = __expf(mrow[t][r] - mnew);
        float ls = 0.f;
        #pragma unroll
        for (int nt = 0; nt < 4; ++nt) {
          float pv = __expf(sv[t][nt][r] - mnew);
          sv[t][nt][r] = pv; ls += pv;
        }
        ls = rsum16(ls);
        lrow[t][r] = lrow[t][r] * alpha + ls;
        mrow[t][r] = mnew;
        #pragma unroll
        for (int nt = 0; nt < 8; ++nt) o[t][nt][r] *= alpha;
      }
      #pragma unroll
      for (int nt = 0; nt < 4; ++nt)
        #pragma unroll
        for (int r = 0; r < 4; ++r)
          Pb[wave*2304 + (t*16 + quad*4 + r)*72 + nt*16 + l16] = f2b_fast(sv[t][nt][r]);
    }

    bf16x8 ap[2][2];
    #pragma unroll
    for (int t = 0; t < 2; ++t)
      #pragma unroll
      for (int k2 = 0; k2 < 2; ++k2)
        ap[t][k2] = *(const bf16x8*)&Pb[wave*2304 + (t*16 + l16)*72 + k2*32 + quad*8];
    #pragma unroll
    for (int k2 = 0; k2 < 2; ++k2) {
      #pragma unroll
      for (int nt = 0; nt < 8; ++nt) {
        bf16x8 bv = *(const bf16x8*)&Vt[(nt*16 + l16)*72 + k2*32 + quad*8];
        o[1][nt] = __builtin_amdgcn_mfma_f32_16x16x32_bf16(ap[1][k2], bv, o[1][nt], 0, 0, 0);
        if (actA) o[0][nt] = __builtin_amdgcn_mfma_f32_16x16x32_bf16(ap[0][k2], bv, o[0][nt], 0, 0, 0);
      }
    }
    __syncthreads();
  }

  #pragma unroll
  for (int t = 0; t < 2; ++t) {
    int qrb = (t ? qb : qa) * 64;
    #pragma unroll
    for (int nt = 0; nt < 8; ++nt)
      #pragma unroll
      for (int r = 0; r < 4; ++r) {
        int q = qrb + wave*16 + quad*4 + r;
        float v = o[t][nt][r] / lrow[t][r];
        O[((size_t)(b*SS + q)) * DD + h*DHH + nt*16 + l16] = f2b(v);
      }
  }
}

extern "C" void kernel_launch(void* const* d_in, const int* in_sizes, int n_in,
                              void* d_out, int out_size, void* d_ws, size_t ws_size,
                              hipStream_t stream) {
  const float* x  = (const float*)d_in[0];
  const int* pos  = (const int*)d_in[1];
  const float* Wq = (const float*)d_in[2];
  const float* Wk = (const float*)d_in[3];
  const float* Wv = (const float*)d_in[4];
  const float* Wo = (const float*)d_in[5];

  char* ws = (char*)d_ws;
  short* xb  = (short*)(ws);
  short* wqb = (short*)(ws + 16777216);
  short* wkb = (short*)(ws + 25165824);
  short* wvb = (short*)(ws + 33554432);
  short* wob = (short*)(ws + 41943040);
  short* Qb  = (short*)(ws + 50331648);
  short* Kb  = (short*)(ws + 67108864);
  short* Vb  = (short*)(ws + 83886080);
  short* Ob  = (short*)(ws + 100663296);
  short* Pp  = (short*)(ws + 50331648);   // split-K partials, reuses dead Qb+Kb after attn

  cvt_all<<<24576, 256, 0, stream>>>(x, Wq, Wk, Wv, Wo, xb, wqb, wkb, wvb, wob);

  dim3 gq(48, MM/128);       // fused QKV: 1536 blocks
  gemm_qkv<<<gq, 256, 0, stream>>>(xb, wqb, wkb, wvb, Qb, Kb, Vb);

  dim3 gr(4096, 2);
  rope2<<<gr, 256, 0, stream>>>(Qb, Kb, pos);

  dim3 ga(16, BB*HH);        // paired tiles: 512 balanced blocks
  attn<<<ga, 256, 0, stream>>>(Qb, Kb, Vb, Ob);

  dim3 go(DD/128, MM/128, 2);   // split-K=2: 1024 blocks
  gemm_o_sk<<<go, 256, 0, stream>>>(Ob, wob, Pp);

  add_out<<<(MM*DD/4)/256, 256, 0, stream>>>(Pp, (float*)d_out, MM*DD/4);
}

// Round 6
// 462.222 us; speedup vs baseline: 1.0771x; 1.0771x over previous
//
#include <hip/hip_runtime.h>
#include <hip/hip_bf16.h>
#include <math.h>

#define BB 2
#define SS 2048
#define DD 2048
#define HH 16
#define DHH 128
#define MM (BB*SS)   // 4096

typedef __attribute__((ext_vector_type(8))) short bf16x8;
typedef __attribute__((ext_vector_type(4))) float f32x4;

#define AS1 __attribute__((address_space(1)))
#define AS3 __attribute__((address_space(3)))
#define GLOAD_LDS16(g, l) __builtin_amdgcn_global_load_lds((const AS1 void*)(g), (AS3 void*)(l), 16, 0, 0)

__device__ __forceinline__ float b2f(short s) {
  union { unsigned int u; float f; } v;
  v.u = ((unsigned int)(unsigned short)s) << 16;
  return v.f;
}
__device__ __forceinline__ short f2b(float f) {
  union { float f; unsigned int u; } v; v.f = f;
  unsigned int u = v.u;
  u += 0x7fffu + ((u >> 16) & 1u);   // round-to-nearest-even
  return (short)(u >> 16);
}
// fast round-half-up; valid for non-negative finite values (P in [0,1])
__device__ __forceinline__ short f2b_fast(float f) {
  union { float f; unsigned int u; } v; v.f = f;
  return (short)((v.u + 0x8000u) >> 16);
}

// ---- DPP helpers (VALU pipe, no LDS ops) ----
template<int CTRL>
__device__ __forceinline__ float dppf(float x) {
  int xi = __builtin_bit_cast(int, x);
  int r = __builtin_amdgcn_update_dpp(0, xi, CTRL, 0xf, 0xf, true);
  return __builtin_bit_cast(float, r);
}
__device__ __forceinline__ float rmax16(float x) {
  x = fmaxf(x, dppf<0xB1>(x));   // quad_perm xor1
  x = fmaxf(x, dppf<0x4E>(x));   // quad_perm xor2
  x = fmaxf(x, dppf<0x141>(x));  // row_half_mirror
  x = fmaxf(x, dppf<0x140>(x));  // row_mirror
  return x;
}
__device__ __forceinline__ float rsum16(float x) {
  x += dppf<0xB1>(x);
  x += dppf<0x4E>(x);
  x += dppf<0x141>(x);
  x += dppf<0x140>(x);
  return x;
}

// ---------------- fp32 -> bf16 convert, all 5 tensors in one launch ----------------
__global__ void cvt_all(const float* __restrict__ x,  const float* __restrict__ wq,
                        const float* __restrict__ wk, const float* __restrict__ wv,
                        const float* __restrict__ wo,
                        short* __restrict__ xb,  short* __restrict__ wqb,
                        short* __restrict__ wkb, short* __restrict__ wvb,
                        short* __restrict__ wob) {
  int i = blockIdx.x * blockDim.x + threadIdx.x;   // float4 index
  const float* src; short* dst; int off;
  if (i < 2097152) { src = x; dst = xb; off = i; }
  else {
    int j = i - 2097152;
    int w = j >> 20; off = j & 1048575;
    src = (w == 0) ? wq : (w == 1) ? wk : (w == 2) ? wv : wo;
    dst = (w == 0) ? wqb : (w == 1) ? wkb : (w == 2) ? wvb : wob;
  }
  float4 v = ((const float4*)src)[i < 2097152 ? off : off];
  short4 o;
  o.x = f2b(v.x); o.y = f2b(v.y); o.z = f2b(v.z); o.w = f2b(v.w);
  ((short4*)dst)[off] = o;
}

// ---------------- Fused QKV GEMM, 256x128 tiles, RoPE fused in epilogue ----------
// A: bf16 [M,2048]; W*: bf16 [2048,2048]; writes bf16 [B,H,S,DH].
// Q/K get interleaved RoPE applied in-register (DPP pair exchange);
// Q additionally scaled by 1/sqrt(DH).
__global__ __launch_bounds__(256, 2)
void gemm_qkv(const short* __restrict__ A,
              const short* __restrict__ Wq, const short* __restrict__ Wk,
              const short* __restrict__ Wv, const int* __restrict__ pos,
              short* __restrict__ Qo, short* __restrict__ Ko, short* __restrict__ Vo) {
  __shared__ __align__(16) short As[256*64];   // 32 KB
  __shared__ __align__(16) short Bs[128*64];   // 16 KB
  const int tid = threadIdx.x;
  const int lane = tid & 63;
  const int wave = tid >> 6;
  const int quad = lane >> 4, l16 = lane & 15;
  const int wsel = blockIdx.x >> 4;            // 0=Q 1=K 2=V
  const short* Bw = Wq; short* Cout = Qo;
  if (wsel == 1) { Bw = Wk; Cout = Ko; }
  else if (wsel == 2) { Bw = Wv; Cout = Vo; }
  const int bn = (blockIdx.x & 15) * 128;
  const int bm = blockIdx.y * 256;
  const int K = DD;

  const int srow = tid >> 3;        // 0..31
  const int scol = (tid & 7) * 8;
  const short* aBase = A + (size_t)(bm + srow) * K + scol;
  const short* bBase = Bw + (size_t)(bn + srow) * K + scol;
  // wave owns rows [bm + wave*64, +64), all 128 cols
  f32x4 acc[4][8] = {};

  for (int k0 = 0; k0 < K; k0 += 64) {
    #pragma unroll
    for (int j = 0; j < 8; ++j)
      GLOAD_LDS16(aBase + (size_t)j * 32 * K + k0, As + j * 2048 + wave * 512);
    #pragma unroll
    for (int j = 0; j < 4; ++j)
      GLOAD_LDS16(bBase + (size_t)j * 32 * K + k0, Bs + j * 2048 + wave * 512);
    __syncthreads();
    #pragma unroll
    for (int kk = 0; kk < 64; kk += 32) {
      bf16x8 af[4], bf[8];
      #pragma unroll
      for (int t = 0; t < 4; ++t)
        af[t] = *(const bf16x8*)&As[(wave*64 + t*16 + l16) * 64 + kk + quad*8];
      #pragma unroll
      for (int t = 0; t < 8; ++t)
        bf[t] = *(const bf16x8*)&Bs[(t*16 + l16) * 64 + kk + quad*8];
      #pragma unroll
      for (int mt = 0; mt < 4; ++mt)
        #pragma unroll
        for (int nt = 0; nt < 8; ++nt)
          acc[mt][nt] = __builtin_amdgcn_mfma_f32_16x16x32_bf16(af[mt], bf[nt], acc[mt][nt], 0, 0, 0);
    }
    __syncthreads();
  }

  // ---- RoPE in-register for Q/K (pairs = adjacent lanes via DPP xor1) ----
  if (wsel < 2) {
    const float post = (wsel == 0) ? 0.08838834764831845f : 1.0f;
    float fr[8];
    #pragma unroll
    for (int nt = 0; nt < 8; ++nt) {
      int pi = nt*8 + (l16 >> 1);                 // pair index 0..63
      fr[nt] = __expf(-0.14391156831f * (float)pi);  // theta^(-pi/64)
    }
    const float sgn = (l16 & 1) ? 1.0f : -1.0f;
    #pragma unroll
    for (int mt = 0; mt < 4; ++mt) {
      #pragma unroll
      for (int r = 0; r < 4; ++r) {
        int m = bm + wave*64 + mt*16 + quad*4 + r;
        float fp = (float)pos[m & 2047];
        #pragma unroll
        for (int nt = 0; nt < 8; ++nt) {
          float v = acc[mt][nt][r];
          float p = dppf<0xB1>(v);               // partner (d^1) value
          float ang = fp * fr[nt];
          float sn = __sinf(ang), cs = __cosf(ang);
          acc[mt][nt][r] = (v * cs + sgn * p * sn) * post;
        }
      }
    }
  }

  #pragma unroll
  for (int mt = 0; mt < 4; ++mt)
    #pragma unroll
    for (int nt = 0; nt < 8; ++nt)
      #pragma unroll
      for (int r = 0; r < 4; ++r) {
        int m = bm + wave*64 + mt*16 + quad*4 + r;
        int n = bn + nt*16 + l16;
        int b = m >> 11, s = m & 2047;
        int h = n >> 7,  d = n & 127;
        Cout[(((size_t)(b*HH + h)*SS + s)*DHH) + d] = f2b(acc[mt][nt][r]);
      }
}

// ---------------- O-projection GEMM (fp32 out, direct) ----------------
__global__ __launch_bounds__(256)
void gemm_o(const short* __restrict__ A, const short* __restrict__ Bw,
            float* __restrict__ Cout) {
  __shared__ __align__(16) short As[128*64];
  __shared__ __align__(16) short Bs[128*64];
  const int tid = threadIdx.x;
  const int lane = tid & 63;
  const int wave = tid >> 6;
  const int wm = wave >> 1, wn = wave & 1;
  const int quad = lane >> 4, l16 = lane & 15;
  const int bm = blockIdx.y * 128, bn = blockIdx.x * 128;
  const int K = DD;

  const int srow = tid >> 3;
  const int scol = (tid & 7) * 8;
  const short* aBase = A + (size_t)(bm + srow) * K + scol;
  const short* bBase = Bw + (size_t)(bn + srow) * K + scol;
  f32x4 acc[4][4] = {};

  for (int k0 = 0; k0 < K; k0 += 64) {
    #pragma unroll
    for (int j = 0; j < 4; ++j) {
      GLOAD_LDS16(aBase + (size_t)j * 32 * K + k0, As + j * 2048 + wave * 512);
      GLOAD_LDS16(bBase + (size_t)j * 32 * K + k0, Bs + j * 2048 + wave * 512);
    }
    __syncthreads();
    #pragma unroll
    for (int kk = 0; kk < 64; kk += 32) {
      bf16x8 af[4], bf[4];
      #pragma unroll
      for (int t = 0; t < 4; ++t)
        af[t] = *(const bf16x8*)&As[(wm*64 + t*16 + l16) * 64 + kk + quad*8];
      #pragma unroll
      for (int t = 0; t < 4; ++t)
        bf[t] = *(const bf16x8*)&Bs[(wn*64 + t*16 + l16) * 64 + kk + quad*8];
      #pragma unroll
      for (int mt = 0; mt < 4; ++mt)
        #pragma unroll
        for (int nt = 0; nt < 4; ++nt)
          acc[mt][nt] = __builtin_amdgcn_mfma_f32_16x16x32_bf16(af[mt], bf[nt], acc[mt][nt], 0, 0, 0);
    }
    __syncthreads();
  }

  #pragma unroll
  for (int mt = 0; mt < 4; ++mt)
    #pragma unroll
    for (int nt = 0; nt < 4; ++nt)
      #pragma unroll
      for (int r = 0; r < 4; ++r) {
        int m = bm + wm*64 + mt*16 + quad*4 + r;
        int n = bn + wn*64 + nt*16 + l16;
        Cout[(size_t)m * DD + n] = acc[mt][nt][r];
      }
}

// ---------------- Flash attention (causal), paired 64-row Q tiles ----------------
// Q pre-scaled by 1/sqrt(DH). Block p handles Q tiles qa=p, qb=31-p (33 computes each).
__global__ __launch_bounds__(256, 2)
void attn(const short* __restrict__ Q, const short* __restrict__ K,
          const short* __restrict__ V, short* __restrict__ O) {
  __shared__ __align__(16) short Ks[64*136];    // [key][dim], stride 136
  __shared__ __align__(16) short Vt[128*72];    // [dim][key], stride 72
  __shared__ __align__(16) short Pb[4*32*72];   // per-wave P
  const int tid = threadIdx.x;
  const int lane = tid & 63, wave = tid >> 6;
  const int quad = lane >> 4, l16 = lane & 15;
  const int p = blockIdx.x;            // 0..15
  const int qa = p, qb = 31 - p;
  const int bh = blockIdx.y;
  const int b = bh >> 4, h = bh & 15;
  const short* Kg = K + (size_t)bh * SS * DHH;
  const short* Vg = V + (size_t)bh * SS * DHH;

  bf16x8 aq[2][4];
  #pragma unroll
  for (int t = 0; t < 2; ++t) {
    int qrb = (t ? qb : qa) * 64;
    const short* qp = Q + ((size_t)bh * SS + qrb + wave*16 + l16) * DHH + quad*8;
    #pragma unroll
    for (int ks = 0; ks < 4; ++ks) aq[t][ks] = *(const bf16x8*)(qp + ks*32);
  }

  f32x4 o[2][8] = {};
  float mrow[2][4], lrow[2][4];
  #pragma unroll
  for (int t = 0; t < 2; ++t)
    #pragma unroll
    for (int r = 0; r < 4; ++r) { mrow[t][r] = -1e30f; lrow[t][r] = 0.f; }

  const int krow = tid >> 2;
  const int kseg = (tid & 3) * 32;
  const int vkp  = (tid & 31) * 2;
  const int vds  = (tid >> 5) * 16;

  const int nkt = qb + 1;
  int4 kreg[4], vreg[4];
  {
    const short* kp = Kg + (size_t)krow * DHH + kseg;
    #pragma unroll
    for (int j = 0; j < 4; ++j) kreg[j] = *(const int4*)(kp + j*8);
    const short* vp = Vg + (size_t)vkp * DHH + vds;
    vreg[0] = *(const int4*)(vp);
    vreg[1] = *(const int4*)(vp + 8);
    vreg[2] = *(const int4*)(vp + DHH);
    vreg[3] = *(const int4*)(vp + DHH + 8);
  }

  for (int kt = 0; kt < nkt; ++kt) {
    #pragma unroll
    for (int j = 0; j < 4; ++j)
      *(int4*)&Ks[krow*136 + kseg + j*8] = kreg[j];
    {
      const short* s0 = (const short*)&vreg[0];
      const short* s1 = (const short*)&vreg[2];
      #pragma unroll
      for (int e = 0; e < 16; ++e) {
        int val = (int)(unsigned short)s0[e] | ((int)(unsigned short)s1[e] << 16);
        *(int*)&Vt[(vds + e)*72 + vkp] = val;
      }
    }
    __syncthreads();

    if (kt + 1 < nkt) {
      const short* kp = Kg + (size_t)((kt+1)*64 + krow) * DHH + kseg;
      #pragma unroll
      for (int j = 0; j < 4; ++j) kreg[j] = *(const int4*)(kp + j*8);
      const short* vp = Vg + (size_t)((kt+1)*64 + vkp) * DHH + vds;
      vreg[0] = *(const int4*)(vp);
      vreg[1] = *(const int4*)(vp + 8);
      vreg[2] = *(const int4*)(vp + DHH);
      vreg[3] = *(const int4*)(vp + DHH + 8);
    }

    const bool actA = (kt <= qa);

    float sv[2][4][4];
    #pragma unroll
    for (int nt = 0; nt < 4; ++nt) {
      f32x4 a1 = {0.f,0.f,0.f,0.f}, a0 = {0.f,0.f,0.f,0.f};
      #pragma unroll
      for (int ks = 0; ks < 4; ++ks) {
        bf16x8 bk = *(const bf16x8*)&Ks[(nt*16 + l16)*136 + ks*32 + quad*8];
        a1 = __builtin_amdgcn_mfma_f32_16x16x32_bf16(aq[1][ks], bk, a1, 0, 0, 0);
        if (actA) a0 = __builtin_amdgcn_mfma_f32_16x16x32_bf16(aq[0][ks], bk, a0, 0, 0, 0);
      }
      #pragma unroll
      for (int r = 0; r < 4; ++r) {
        sv[1][nt][r] = a1[r];
        sv[0][nt][r] = a0[r];
      }
    }
    #pragma unroll
    for (int t = 0; t < 2; ++t) {
      int tq = t ? qb : qa;
      if (kt == tq) {
        #pragma unroll
        for (int nt = 0; nt < 4; ++nt)
          #pragma unroll
          for (int r = 0; r < 4; ++r)
            if (nt*16 + l16 > wave*16 + quad*4 + r) sv[t][nt][r] = -1e30f;
      }
    }

    #pragma unroll
    for (int t = 0; t < 2; ++t) {
      if (t == 0 && !actA) continue;
      #pragma unroll
      for (int r = 0; r < 4; ++r) {
        float mx = fmaxf(fmaxf(sv[t][0][r], sv[t][1][r]), fmaxf(sv[t][2][r], sv[t][3][r]));
        mx = rmax16(mx);
        float mnew = fmaxf(mrow[t][r], mx);
        float alpha = __expf(mrow[t][r] - mnew);
        float ls = 0.f;
        #pragma unroll
        for (int nt = 0; nt < 4; ++nt) {
          float pv = __expf(sv[t][nt][r] - mnew);
          sv[t][nt][r] = pv; ls += pv;
        }
        ls = rsum16(ls);
        lrow[t][r] = lrow[t][r] * alpha + ls;
        mrow[t][r] = mnew;
        #pragma unroll
        for (int nt = 0; nt < 8; ++nt) o[t][nt][r] *= alpha;
      }
      #pragma unroll
      for (int nt = 0; nt < 4; ++nt)
        #pragma unroll
        for (int r = 0; r < 4; ++r)
          Pb[wave*2304 + (t*16 + quad*4 + r)*72 + nt*16 + l16] = f2b_fast(sv[t][nt][r]);
    }

    bf16x8 ap[2][2];
    #pragma unroll
    for (int t = 0; t < 2; ++t)
      #pragma unroll
      for (int k2 = 0; k2 < 2; ++k2)
        ap[t][k2] = *(const bf16x8*)&Pb[wave*2304 + (t*16 + l16)*72 + k2*32 + quad*8];
    #pragma unroll
    for (int k2 = 0; k2 < 2; ++k2) {
      #pragma unroll
      for (int nt = 0; nt < 8; ++nt) {
        bf16x8 bv = *(const bf16x8*)&Vt[(nt*16 + l16)*72 + k2*32 + quad*8];
        o[1][nt] = __builtin_amdgcn_mfma_f32_16x16x32_bf16(ap[1][k2], bv, o[1][nt], 0, 0, 0);
        if (actA) o[0][nt] = __builtin_amdgcn_mfma_f32_16x16x32_bf16(ap[0][k2], bv, o[0][nt], 0, 0, 0);
      }
    }
    __syncthreads();
  }

  #pragma unroll
  for (int t = 0; t < 2; ++t) {
    int qrb = (t ? qb : qa) * 64;
    #pragma unroll
    for (int nt = 0; nt < 8; ++nt)
      #pragma unroll
      for (int r = 0; r < 4; ++r) {
        int q = qrb + wave*16 + quad*4 + r;
        float v = o[t][nt][r] / lrow[t][r];
        O[((size_t)(b*SS + q)) * DD + h*DHH + nt*16 + l16] = f2b(v);
      }
  }
}

extern "C" void kernel_launch(void* const* d_in, const int* in_sizes, int n_in,
                              void* d_out, int out_size, void* d_ws, size_t ws_size,
                              hipStream_t stream) {
  const float* x  = (const float*)d_in[0];
  const int* pos  = (const int*)d_in[1];
  const float* Wq = (const float*)d_in[2];
  const float* Wk = (const float*)d_in[3];
  const float* Wv = (const float*)d_in[4];
  const float* Wo = (const float*)d_in[5];

  char* ws = (char*)d_ws;
  short* xb  = (short*)(ws);
  short* wqb = (short*)(ws + 16777216);
  short* wkb = (short*)(ws + 25165824);
  short* wvb = (short*)(ws + 33554432);
  short* wob = (short*)(ws + 41943040);
  short* Qb  = (short*)(ws + 50331648);
  short* Kb  = (short*)(ws + 67108864);
  short* Vb  = (short*)(ws + 83886080);
  short* Ob  = (short*)(ws + 100663296);

  cvt_all<<<24576, 256, 0, stream>>>(x, Wq, Wk, Wv, Wo, xb, wqb, wkb, wvb, wob);

  dim3 gq(48, MM/256);       // fused QKV: 768 blocks, 256x128 tiles, rope fused
  gemm_qkv<<<gq, 256, 0, stream>>>(xb, wqb, wkb, wvb, pos, Qb, Kb, Vb);

  dim3 ga(16, BB*HH);        // paired tiles: 512 balanced blocks
  attn<<<ga, 256, 0, stream>>>(Qb, Kb, Vb, Ob);

  dim3 go(DD/128, MM/128);   // 512 blocks, direct fp32 out
  gemm_o<<<go, 256, 0, stream>>>(Ob, wob, (float*)d_out);
}